// Round 4
// baseline (261.063 us; speedup 1.0000x reference)
//
#include <hip/hip_runtime.h>

// Backward (bilinear) warp: out[b,c,h,w] = bilinear_sample(input[b,c], w+flow_x, h+flow_y)
// Shapes: input [4,32,512,512] f32, flow [4,2,512,512] f32, out [4,32,512,512] f32.
//
// R6: two independent barrier domains per CU with ZERO traffic growth.
// R5 (90us) analysis: all pipes <30% busy; per-channel period is dominated by
// barrier-max over 16 waves (random LDS-conflict draws + stage completion +
// rare fallback excursions) with nothing else to run on the CU. R4's sibling-
// block attempt regressed, but it confounded the test with 1.5x staged traffic
// (64x32 tiles = 6x apron amplification). This version removes the confound:
//  - keep 64x64 tiles (4x amplification); split the CHANNEL range instead:
//    512 blocks = 256 tiles x 2 channel-halves (16 channels each).
//  - 512 threads (8 waves), 8 px/thread; ONE 64 KiB buffer -> 2 blocks/CU.
//    Total staged bytes per CU identical to R5 (2 x 16 x 64KB = 1 x 32 x 64KB).
//  - per channel: gather -> lgkm(0) -> barrier(WAR) -> stage(c+1) -> stores
//    -> vmcnt(8) -> barrier(RAW). Stage latency is exposed inside a block
//    (single buffer) BY DESIGN: the sibling block at an independent phase
//    fills the CU during the stage wait and the barrier-max tails.
//  - stores issued AFTER the stage loads; vmcnt(8) drains the 8 stage loads
//    (+ last channel's stores, long retired) and never drains current stores.
//  - XCD-aware bijective swizzle: 64 contiguous tiles of one channel-half per
//    XCD (keeps the apron L2 sharing that cut FETCH 127->87 MB).

constexpr int B = 4, C = 32, H = 512, W = 512;
constexpr int HW = H * W;
constexpr int TILE = 64;
constexpr int CHALF = 16;       // channels per block
constexpr int APRON = 31;       // covers |flow| <= 31 (3.87 sigma of N(0,8))
constexpr int RH = 128;         // staged rows  (64 + 31 + 31 + 1, padded)
constexpr int RW = 128;         // staged cols (dwords): 64 + 32 + 31 + 1 = 128
constexpr int BUF = RH * RW;    // 16384 dwords = 64 KiB

typedef __attribute__((address_space(1))) const unsigned int gas_u32;
typedef __attribute__((address_space(3))) unsigned int las_u32;

__global__ __launch_bounds__(512, 4) void warp_tile_kernel(
    const float* __restrict__ input,
    const float* __restrict__ flow,
    float* __restrict__ out)
{
    __shared__ float s[BUF];              // 64 KiB, single buffer

    // XCD-aware bijective swizzle over 512 blocks (512 % 8 == 0):
    // seq = xcd*64 + idx; consecutive seq within an XCD = 64 consecutive
    // tiles of ONE channel-half (spatially adjacent -> shared aprons in L2).
    int bid0 = (int)blockIdx.x;
    int seq = (bid0 & 7) * 64 + (bid0 >> 3);
    int tileid = seq & 255;               // [b:4][ty:8][tx:8]
    int c0 = (seq >> 8) * CHALF;          // channel half: 0 or 16

    int tx = tileid & 7;
    int ty = (tileid >> 3) & 7;
    int b  = tileid >> 6;
    int tx0 = tx * TILE, ty0 = ty * TILE;

    // virtual region origin (may be out of image; staging sources are clamped
    // per-lane, and clamped/garbage cells are provably never gathered)
    int rx0 = tx0 - 32;                   // 32 keeps RW=128 & 16B alignment
    int ry0 = ty0 - APRON;

    int tid  = (int)threadIdx.x;
    int lane = tid & 63;
    int wv   = tid >> 6;                  // wave id 0..7
    int cl   = tid & 63;                  // output col within tile
    int rl   = tid >> 6;                  // output row group (rows rl + 8p)

    // ---- staging source offsets (channel-relative dword offsets, per lane) ----
    // wave wv, issue i (0..7) stages region rows r=16*wv+2*i and r+1:
    //   lanes 0..31 -> row r cols 4L..4L+3, lanes 32..63 -> row r+1.
    int soff[8];
    int sr[8];
    {
        int lrow = lane >> 5;                        // 0 or 1
        int lc   = (lane & 31) << 2;                 // 0..124
        int gcol = min(max(rx0 + lc, 0), W - 4);     // 16B-aligned, in-row
        #pragma unroll
        for (int i = 0; i < 8; ++i) {
            int r = 16 * wv + 2 * i;                 // wave-uniform
            sr[i] = r;
            int grow = min(max(ry0 + r + lrow, 0), H - 1);
            soff[i] = grow * W + gcol;
        }
    }

    // ---- per-pixel precompute (8 px/thread), reused across 16 channels ----
    float wa[8], wb_[8], wc_[8], wd_[8];
    int a0[8], a1[8];
    int opix0 = (ty0 + rl) * W + tx0 + cl;

    #pragma unroll
    for (int p = 0; p < 8; ++p) {
        int h = ty0 + rl + 8 * p;
        int w = tx0 + cl;
        int pix = h * W + w;
        float fx = flow[(b * 2 + 0) * HW + pix];
        float fy = flow[(b * 2 + 1) * HW + pix];
        float x = fminf(fmaxf((float)w + fx, 0.0f), (float)(W - 1));
        float y = fminf(fmaxf((float)h + fy, 0.0f), (float)(H - 1));
        float x0f = floorf(x), y0f = floorf(y);
        int x0 = (int)x0f, y0 = (int)y0f;
        int y1 = min(y0 + 1, H - 1);
        float dx = x - x0f, dy = y - y0f;
        // weights use UNCLAMPED x1f=x0f+1, y1f=y0f+1 (matches reference)
        wa[p]  = (1.f - dx) * (1.f - dy);
        wb_[p] = (1.f - dx) * dy;
        wc_[p] = dx * (1.f - dy);
        wd_[p] = dx * dy;
        int ax0 = x0 - rx0, ay0 = y0 - ry0, ay1 = y1 - ry0;
        // need ax0 in [0,RW-2] (reads ax0+1), ay0>=0, ay1<=RH-1
        bool inreg = (ax0 >= 0) && (ax0 <= RW - 2) && (ay0 >= 0) && (ay1 <= RH - 1);
        // at x0==x1 (image right edge) the +1 read hits a staged-garbage col,
        // but its weight wc==dx==0 -> harmless. Same at bottom edge for y.
        a0[p] = inreg ? (ay0 * RW + ax0) : -1;
        a1[p] = ay1 * RW + ax0;
    }

    const float* iplane = input + (size_t)b * C * HW;
    float* oplane = out + (size_t)b * C * HW;

    // async stage of channel c (8 wave-instrs, 16 rows/wave)
    auto stage = [&](int c) {
        const float* gc = iplane + (size_t)c * HW;
        #pragma unroll
        for (int i = 0; i < 8; ++i) {
            __builtin_amdgcn_global_load_lds(
                (gas_u32*)(gc + soff[i]),
                (las_u32*)(&s[sr[i] * RW]),
                16, 0, 0);
        }
    };

    stage(c0);
    __syncthreads();   // prologue: vmcnt(0) + barrier (buffer fully staged)

    for (int k = 0; k < CHALF; ++k) {
        int c = c0 + k;

        // ---- gather from LDS + FMA (results held in regs) ----
        float v[8];
        #pragma unroll
        for (int p = 0; p < 8; ++p) {
            if (a0[p] >= 0) {
                float v00 = s[a0[p]],  v01 = s[a0[p] + 1];
                float v10 = s[a1[p]],  v11 = s[a1[p] + 1];
                v[p] = wa[p] * v00 + wc_[p] * v01 + wb_[p] * v10 + wd_[p] * v11;
            } else {
                // outlier (|flow|>APRON, P ~ 2e-4/px): recompute + global gather
                int h = ty0 + rl + 8 * p;
                int w = tx0 + cl;
                int pix = h * W + w;
                float fx = flow[(b * 2 + 0) * HW + pix];
                float fy = flow[(b * 2 + 1) * HW + pix];
                float x = fminf(fmaxf((float)w + fx, 0.0f), (float)(W - 1));
                float y = fminf(fmaxf((float)h + fy, 0.0f), (float)(H - 1));
                float x0f = floorf(x), y0f = floorf(y);
                int x0 = (int)x0f, y0 = (int)y0f;
                int x1 = min(x0 + 1, W - 1), y1 = min(y0 + 1, H - 1);
                float dx = x - x0f, dy = y - y0f;
                const float* pch = iplane + (size_t)c * HW;
                v[p] = (1.f - dx) * (1.f - dy) * pch[y0 * W + x0]
                     + (1.f - dx) * dy         * pch[y1 * W + x0]
                     + dx * (1.f - dy)         * pch[y0 * W + x1]
                     + dx * dy                 * pch[y1 * W + x1];
            }
        }

        // all ds_reads of the buffer are in VGPRs -> WAR-safe to restage
        asm volatile("s_waitcnt lgkmcnt(0)" ::: "memory");
        __builtin_amdgcn_sched_barrier(0);
        __builtin_amdgcn_s_barrier();            // WAR: all waves done reading
        __builtin_amdgcn_sched_barrier(0);

        if (k + 1 < CHALF) stage(c + 1);         // 8 async loads, issued FIRST

        float* oc = oplane + (size_t)c * HW;
        #pragma unroll
        for (int p = 0; p < 8; ++p)
            oc[opix0 + 8 * p * W] = v[p];        // stores AFTER the stage loads

        if (k + 1 < CHALF) {
            // drain the 8 stage loads (+ previous channel's stores, long since
            // retired); leave this channel's 8 stores in flight. Exposed stage
            // latency here is covered by the sibling block on this CU.
            asm volatile("s_waitcnt vmcnt(8)" ::: "memory");
            __builtin_amdgcn_sched_barrier(0);
            __builtin_amdgcn_s_barrier();        // RAW: buffer staged for c+1
            __builtin_amdgcn_sched_barrier(0);
        }
    }
}

extern "C" void kernel_launch(void* const* d_in, const int* in_sizes, int n_in,
                              void* d_out, int out_size, void* d_ws, size_t ws_size,
                              hipStream_t stream) {
    const float* input = (const float*)d_in[0];
    const float* flow  = (const float*)d_in[1];
    float* out = (float*)d_out;

    int grid = B * (H / TILE) * (W / TILE) * (C / CHALF);  // 512 blocks, 2/CU
    warp_tile_kernel<<<grid, 512, 0, stream>>>(input, flow, out);
}